// Round 4
// baseline (85.856 us; speedup 1.0000x reference)
//
#include <hip/hip_runtime.h>
#include <hip/hip_bf16.h>
#include <cstdint>
#include <cstddef>

// Problem constants: B=16, S=2048, E=128, H=768, C=457
constexpr int Bn = 16, Sn = 2048, En = 128, Hn = 768, Cn = 457;
constexpr int NP = 512;                 // padded class dim for logits GEMM
using f32x4  = __attribute__((ext_vector_type(4))) float;
using bf16x8 = __attribute__((ext_vector_type(8))) short;

static __device__ inline unsigned short f2bf(float x) {
  __hip_bfloat16 b = __float2bfloat16(x);
  return *reinterpret_cast<unsigned short*>(&b);
}

// ---------------------------------------------------------------------------
// Kernel 0: bit-pack entities_list. (B,S,E=128) int32 -> (B*S, 4) u32 words.
// One wave packs a token via two 64-lane ballots (coalesced 256B reads).
// ---------------------------------------------------------------------------
__global__ __launch_bounds__(256) void pack_k(
    const int* __restrict__ el, unsigned int* __restrict__ pk)
{
  const int l = threadIdx.x & 63;
  const int gw = blockIdx.x * 4 + (threadIdx.x >> 6);   // 512 waves total
  #pragma unroll 2
  for (int j = 0; j < 64; ++j) {
    const int tok = gw * 64 + j;                        // 0 .. 32767
    const int v0 = el[(size_t)tok * 128 + l];
    const int v1 = el[(size_t)tok * 128 + 64 + l];
    const unsigned long long b0 = __ballot(v0 != 0);
    const unsigned long long b1 = __ballot(v1 != 0);
    if (l == 0) {
      ulonglong2 w; w.x = b0; w.y = b1;
      *reinterpret_cast<ulonglong2*>(pk + (size_t)tok * 4) = w;
    }
  }
}

// ---------------------------------------------------------------------------
// Kernel 1: entity pooling as dense bmm: ent[b] = el[b]^T (128,S) * hid[b]
// (S,64-chunk). A-operand synthesized from packed bits (zero global traffic),
// B-operand f32->bf16 reg-staged. Double-buffered LDS, prefetch-1, one
// barrier per K-step. Epilogue: /len, cast bf16.
// ---------------------------------------------------------------------------
constexpr int PBN = 64, PBK = 32, PLD = 40;   // 80B row stride: b128-aligned
__global__ __launch_bounds__(512) void pool_k(
    const float* __restrict__ hidden,       // (B,S,H)
    const unsigned int* __restrict__ pk,    // (B*S,4) packed membership
    const int* __restrict__ elen,           // (B,E)
    unsigned short* __restrict__ entbf)     // (B*E,H) bf16
{
  const int b = blockIdx.x, n0 = blockIdx.y * PBN;
  const int tid = threadIdx.x, l = tid & 63, wv = tid >> 6;  // 8 waves
  const int wm = wv >> 2, wn = wv & 3;                       // 2 x 4

  __shared__ unsigned short As[2][En][PLD];   // 20.5 KB  (e x s)
  __shared__ unsigned short Bs[2][PBN][PLD];  // 10.2 KB  (h x s)
  __shared__ unsigned int   PKall[Sn * 4];    // 32 KB

  // stage the whole batch's packed membership once
  const unsigned int* pkb = pk + (size_t)b * Sn * 4;
  for (int i = tid; i < Sn * 4; i += 512) PKall[i] = pkb[i];

  const float* hb = hidden + (size_t)b * Sn * Hn + n0;
  const int half = l >> 5, bit = l & 31;

  // stage step kk into buffer bf (f0..f3 preloaded hidden values)
  auto stage = [&](int kk, int bsel, float f0, float f1, float f2, float f3) {
    const int sb = kk * PBK + wv * 4;
    unsigned int w0[4], w1[4];
    #pragma unroll
    for (int i = 0; i < 4; ++i) {
      w0[i] = PKall[(sb + i) * 4 + half];
      w1[i] = PKall[(sb + i) * 4 + 2 + half];
    }
    auto sel = [&](unsigned int w, int hi) -> unsigned int {
      return ((w >> bit) & 1u) ? (hi ? 0x3F800000u : 0x3F80u) : 0u;
    };
    uint2 da, db, dh;
    da.x = sel(w0[0], 0) | sel(w0[1], 1);
    da.y = sel(w0[2], 0) | sel(w0[3], 1);
    db.x = sel(w1[0], 0) | sel(w1[1], 1);
    db.y = sel(w1[2], 0) | sel(w1[3], 1);
    dh.x = (unsigned int)f2bf(f0) | ((unsigned int)f2bf(f1) << 16);
    dh.y = (unsigned int)f2bf(f2) | ((unsigned int)f2bf(f3) << 16);
    *reinterpret_cast<uint2*>(&As[bsel][l]     [wv * 4]) = da;
    *reinterpret_cast<uint2*>(&As[bsel][l + 64][wv * 4]) = db;
    *reinterpret_cast<uint2*>(&Bs[bsel][l]     [wv * 4]) = dh;
  };

  f32x4 acc[4] = {};
  constexpr int NK = Sn / PBK;   // 64

  // prologue: load + stage step 0 (PKall barrier folded in)
  float f0, f1, f2, f3;
  {
    const int sb = wv * 4;
    f0 = hb[(size_t)(sb + 0) * Hn + l];
    f1 = hb[(size_t)(sb + 1) * Hn + l];
    f2 = hb[(size_t)(sb + 2) * Hn + l];
    f3 = hb[(size_t)(sb + 3) * Hn + l];
    __syncthreads();             // PKall visible
    stage(0, 0, f0, f1, f2, f3);
    __syncthreads();
  }

  const int rl = l & 15, kr = (l >> 4) * 8;
  for (int k = 0; k < NK; ++k) {
    const int cur = k & 1;
    if (k + 1 < NK) {            // issue next step's hidden loads early
      const int sb = (k + 1) * PBK + wv * 4;
      f0 = hb[(size_t)(sb + 0) * Hn + l];
      f1 = hb[(size_t)(sb + 1) * Hn + l];
      f2 = hb[(size_t)(sb + 2) * Hn + l];
      f3 = hb[(size_t)(sb + 3) * Hn + l];
    }
    // compute current step
    const bf16x8 bfr = *reinterpret_cast<const bf16x8*>(&Bs[cur][wn * 16 + rl][kr]);
    #pragma unroll
    for (int mi = 0; mi < 4; ++mi) {
      const bf16x8 afr =
          *reinterpret_cast<const bf16x8*>(&As[cur][wm * 64 + mi * 16 + rl][kr]);
      acc[mi] = __builtin_amdgcn_mfma_f32_16x16x32_bf16(afr, bfr, acc[mi], 0, 0, 0);
    }
    if (k + 1 < NK) stage(k + 1, cur ^ 1, f0, f1, f2, f3);
    __syncthreads();             // single barrier per step (dbuf)
  }

  // epilogue: divide by len, cast bf16, store
  const int rg = (l >> 4) * 4;
  const int col = n0 + wn * 16 + rl;
  #pragma unroll
  for (int mi = 0; mi < 4; ++mi) {
    #pragma unroll
    for (int r = 0; r < 4; ++r) {
      const int e = wm * 64 + mi * 16 + rg + r;
      const float inv = 1.0f / (float)elen[b * En + e];
      entbf[(size_t)(b * En + e) * Hn + col] = f2bf(acc[mi][r] * inv);
    }
  }
}

// ---------------------------------------------------------------------------
// Kernel 2: cast W (457,768) f32 -> (512,768) bf16, zero-padding rows >= 457.
// ---------------------------------------------------------------------------
__global__ __launch_bounds__(256) void cast_w_k(
    const float* __restrict__ Wm, unsigned short* __restrict__ wbf)
{
  const int c = blockIdx.x;          // 0..511
  const int tid = threadIdx.x;
  unsigned short* dst = wbf + (size_t)c * Hn;
  if (c < Cn) {
    const float* src = Wm + (size_t)c * Hn;
    #pragma unroll
    for (int j = 0; j < 3; ++j) dst[tid + j * 256] = f2bf(src[tid + j * 256]);
  } else {
    #pragma unroll
    for (int j = 0; j < 3; ++j) dst[tid + j * 256] = 0;
  }
}

// ---------------------------------------------------------------------------
// Kernel 3: logits GEMM. C[2048][512] = A[2048][768] * B^T[512][768], bf16
// MFMA 16x16x32, fp32 accum. Tile 128x64, 4 waves (2x2), BK=32.
// ---------------------------------------------------------------------------
constexpr int BM = 128, BN = 64, BK = 32, LDP = BK + 24;   // 112B row stride
__global__ __launch_bounds__(256) void gemm_k(
    const unsigned short* __restrict__ A,   // (2048,768) bf16
    const unsigned short* __restrict__ Bm,  // (512,768) bf16 (B^T layout)
    float* __restrict__ Cm)                 // (2048,512) f32
{
  __shared__ unsigned short As[BM][LDP];
  __shared__ unsigned short Bs[BN][LDP];
  const int bm = blockIdx.x, bn = blockIdx.y;
  const int tid = threadIdx.x, lane = tid & 63, wv = tid >> 6;
  const int wm = wv >> 1, wn = wv & 1;          // 2x2 wave grid

  f32x4 acc[4][2] = {};

  for (int k0 = 0; k0 < Hn; k0 += BK) {
    #pragma unroll
    for (int i = 0; i < 2; ++i) {
      const int idx = tid + i * 256;
      const int r = idx >> 2, kc = (idx & 3) * 8;
      const unsigned short* src = A + (size_t)(bm * BM + r) * Hn + k0 + kc;
      *reinterpret_cast<ulonglong2*>(&As[r][kc]) =
          *reinterpret_cast<const ulonglong2*>(src);
    }
    {
      const int r = tid >> 2, kc = (tid & 3) * 8;
      const unsigned short* src = Bm + (size_t)(bn * BN + r) * Hn + k0 + kc;
      *reinterpret_cast<ulonglong2*>(&Bs[r][kc]) =
          *reinterpret_cast<const ulonglong2*>(src);
    }
    __syncthreads();

    const int kr = (lane >> 4) * 8, rl = lane & 15;
    bf16x8 af[4], bf[2];
    #pragma unroll
    for (int mi = 0; mi < 4; ++mi)
      af[mi] = *reinterpret_cast<const bf16x8*>(&As[wm * 64 + mi * 16 + rl][kr]);
    #pragma unroll
    for (int ni = 0; ni < 2; ++ni)
      bf[ni] = *reinterpret_cast<const bf16x8*>(&Bs[wn * 32 + ni * 16 + rl][kr]);
    #pragma unroll
    for (int mi = 0; mi < 4; ++mi)
      #pragma unroll
      for (int ni = 0; ni < 2; ++ni)
        acc[mi][ni] = __builtin_amdgcn_mfma_f32_16x16x32_bf16(
            af[mi], bf[ni], acc[mi][ni], 0, 0, 0);
    __syncthreads();
  }

  const int cl = lane & 15, rg = (lane >> 4) * 4;
  #pragma unroll
  for (int mi = 0; mi < 4; ++mi)
    #pragma unroll
    for (int ni = 0; ni < 2; ++ni) {
      const int col = bn * BN + wn * 32 + ni * 16 + cl;
      #pragma unroll
      for (int r = 0; r < 4; ++r) {
        const int row = bm * BM + wm * 64 + mi * 16 + rg + r;
        Cm[(size_t)row * NP + col] = acc[mi][ni][r];
      }
    }
}

// ---------------------------------------------------------------------------
// Kernel 4: CE per entity (one wave each; 4 waves/block). Bias added here.
// ---------------------------------------------------------------------------
__global__ __launch_bounds__(256) void ce_k(
    const float* __restrict__ logits,        // (2048,512)
    const float* __restrict__ bv,            // (457)
    const int* __restrict__ attr,            // (B,E)
    const unsigned char* __restrict__ emask, // (B,E)
    float* __restrict__ nll)                 // (2048)
{
  const int wv = threadIdx.x >> 6, lane = threadIdx.x & 63;
  const int be = blockIdx.x * 4 + wv;
  if (!emask[be]) { if (lane == 0) nll[be] = 0.f; return; }
  const float* row = logits + (size_t)be * NP;

  float mx = -3.4e38f;
  for (int i = lane; i < Cn; i += 64) mx = fmaxf(mx, row[i] + bv[i]);
  #pragma unroll
  for (int o = 32; o; o >>= 1) mx = fmaxf(mx, __shfl_xor(mx, o, 64));
  float sm = 0.f;
  for (int i = lane; i < Cn; i += 64) sm += __expf(row[i] + bv[i] - mx);
  #pragma unroll
  for (int o = 32; o; o >>= 1) sm += __shfl_xor(sm, o, 64);
  if (lane == 0) {
    const int tg = attr[be];
    nll[be] = mx + logf(sm) - (row[tg] + bv[tg]);
  }
}

// ---------------------------------------------------------------------------
// Kernel 5: deterministic final reduction.
// ---------------------------------------------------------------------------
__global__ __launch_bounds__(256) void reduce_k(
    const float* __restrict__ nll,
    const unsigned char* __restrict__ emask,
    float* __restrict__ out)
{
  const int tid = threadIdx.x;
  float s = 0.f, c = 0.f;
  for (int i = tid; i < Bn * En; i += 256) {
    s += nll[i];
    c += (float)emask[i];
  }
  #pragma unroll
  for (int o = 32; o; o >>= 1) {
    s += __shfl_xor(s, o, 64);
    c += __shfl_xor(c, o, 64);
  }
  __shared__ float ws_[4], wc_[4];
  const int wave = tid >> 6, lane = tid & 63;
  if (lane == 0) { ws_[wave] = s; wc_[wave] = c; }
  __syncthreads();
  if (tid == 0) {
    out[0] = (ws_[0] + ws_[1] + ws_[2] + ws_[3]) /
             (wc_[0] + wc_[1] + wc_[2] + wc_[3]);
  }
}

// ---------------------------------------------------------------------------
extern "C" void kernel_launch(void* const* d_in, const int* in_sizes, int n_in,
                              void* d_out, int out_size, void* d_ws, size_t ws_size,
                              hipStream_t stream) {
  const float* hidden        = (const float*)d_in[0];
  const int* attr            = (const int*)d_in[3];
  const int* el              = (const int*)d_in[4];
  const int* elen            = (const int*)d_in[5];
  const unsigned char* emask = (const unsigned char*)d_in[6];
  const float* Wm            = (const float*)d_in[7];
  const float* bv            = (const float*)d_in[8];

  unsigned short* entbf = (unsigned short*)d_ws;            // 2048*768 bf16
  unsigned short* wbf   = entbf + (size_t)Bn * En * Hn;     // 512*768 bf16
  float* logits = (float*)(wbf + (size_t)NP * Hn);          // 2048*512 f32
  float* nll    = logits + (size_t)Bn * En * NP;            // 2048 f32
  unsigned int* pkbuf = (unsigned int*)(nll + Bn * En);     // B*S*4 u32

  hipLaunchKernelGGL(pack_k, dim3(128), dim3(256), 0, stream, el, pkbuf);
  hipLaunchKernelGGL(pool_k, dim3(Bn, Hn / PBN), dim3(512), 0, stream,
                     hidden, pkbuf, elen, entbf);
  hipLaunchKernelGGL(cast_w_k, dim3(NP), dim3(256), 0, stream, Wm, wbf);
  hipLaunchKernelGGL(gemm_k, dim3(Bn * En / BM, NP / BN), dim3(256), 0, stream,
                     entbf, wbf, logits);
  hipLaunchKernelGGL(ce_k, dim3(Bn * En / 4), dim3(256), 0, stream,
                     logits, bv, attr, emask, nll);
  hipLaunchKernelGGL(reduce_k, dim3(1), dim3(256), 0, stream,
                     nll, emask, (float*)d_out);
}